// Round 11
// baseline (590.824 us; speedup 1.0000x reference)
//
#include <hip/hip_runtime.h>
#include <math.h>

// NeuralTPP: B=4096, L=512, H=HH=32 — register-resident recurrence.
// Block = 128 thr = 2 waves, 16 seqs/block, 256 blocks (1 block/CU).
// Wave A: ENTIRE GRU recurrence in registers — h lives in hreg[8], which is
// exactly the next step's MFMA B-fragment (R5-verified zero-repack row
// permutation). 8 MFMAs/step (r,z,n,p tiles), sigma/tanh chains, h update.
// NO LDS, NO barrier dependency on the critical path.
// Wave B: intensity tail (tanh + 4-lane reduce + f16 pack to ibuf), lagged
// one step behind A via double-buffered 2KB pre-act buffer; 1 barrier/step.
// Phase 2: softplus/log/sigmoid over 16x512 (raw,v2) items, both waves.

constexpr int Bn = 4096;
constexpr int Ln = 512;
constexpr float EPSf = 1e-8f;

typedef _Float16 f16x8 __attribute__((ext_vector_type(8)));
typedef float    f32x4 __attribute__((ext_vector_type(4)));

__device__ __forceinline__ float sigmoidf_(float x) {
    return __fdividef(1.0f, 1.0f + __expf(-x));
}
__device__ __forceinline__ float softplusf_(float x) {
    return fmaxf(x, 0.0f) + __logf(1.0f + __expf(-fabsf(x)));
}

union PK2 { _Float16 f[2]; unsigned u; };

__global__ __launch_bounds__(128, 1)
void tpp_main(const float* __restrict__ deltas,
              const float* __restrict__ mask,
              const float* __restrict__ w_ih,
              const float* __restrict__ w_hh,
              const float* __restrict__ b_ih,
              const float* __restrict__ b_hh,
              const float* __restrict__ w1,
              const float* __restrict__ b1,
              const float* __restrict__ w2,
              const float* __restrict__ b2,
              float* __restrict__ partials)   // [2 * gridDim.x]
{
    const int tid = threadIdx.x;
    const int w   = tid >> 6;            // 0 = recurrence wave A, 1 = intensity wave B
    const int l   = tid & 63;
    const int c   = l & 15;              // batch column / A-tile row
    const int g   = l >> 4;              // k-group & C row-group
    const int b0  = blockIdx.x * 16;

    __shared__ float2   tm[16][514];                     // (tau, mask)   ~66 KB
    __shared__ unsigned ibuf[16 * 520];                  // packed(raw,v2) ~33 KB
    __shared__ __align__(16) _Float16 pbuf[2][16][40];   // p pre-acts      2.5 KB

    // ---- stage (tau, mask) into LDS ----
    for (int q = tid; q < 16 * 128; q += 128) {
        const int cc = q >> 7;
        const int t4 = (q & 127) << 2;
        const float4 dv = *(const float4*)(deltas + (size_t)(b0 + cc) * Ln + t4);
        const float4 mv = *(const float4*)(mask   + (size_t)(b0 + cc) * Ln + t4);
        tm[cc][t4 + 0] = make_float2(dv.x, mv.x);
        tm[cc][t4 + 1] = make_float2(dv.y, mv.y);
        tm[cc][t4 + 2] = make_float2(dv.z, mv.z);
        tm[cc][t4 + 3] = make_float2(dv.w, mv.w);
    }

    // ---- per-wave constants ----
    f16x8 Af[8];                                  // wave A: all 8 A-tiles
    float wrA[8], wrB[8], wzA[8], wzB[8];
    float wnA[8], wnB[8], wnC[8], wpA[8], wpB[8]; // wave A per-unit scalars
    float w2v[8], civ[8], civs = 0.0f, b2v = 0.0f; // wave B scalars
    float hreg[8];

    if (w == 0) {
        const int ub = 8 * (c >> 2) + (c & 3);
        const int j0 = 8 * g;
#pragma unroll
        for (int T = 0; T < 8; ++T) {
            const int G = T >> 1, p = T & 1;
            const int up = ub + 4 * p;
            const float* src =
                (G == 0) ? (w_hh + (size_t)up * 32 + j0) :
                (G == 1) ? (w_hh + (size_t)(32 + up) * 32 + j0) :
                (G == 2) ? (w_hh + (size_t)(64 + up) * 32 + j0) :
                           (w1   + (size_t)up * 33 + 1 + j0);
#pragma unroll
            for (int e = 0; e < 8; ++e) Af[T][e] = (_Float16)src[e];
        }
#pragma unroll
        for (int e = 0; e < 8; ++e) {
            const int u = 8 * g + e;
            wrA[e] = w_ih[u];
            wrB[e] = b_ih[u] + b_hh[u];
            wzA[e] = w_ih[32 + u];
            wzB[e] = b_ih[32 + u] + b_hh[32 + u];
            wnA[e] = w_ih[64 + u];
            wnB[e] = b_ih[64 + u];
            wnC[e] = b_hh[64 + u];
            wpA[e] = w1[(size_t)u * 33];
            wpB[e] = b1[u];
            hreg[e] = 0.0f;
        }
    } else {
#pragma unroll
        for (int e = 0; e < 8; ++e) {
            const int u = 8 * g + e;
            w2v[e] = w2[u];
            civ[e] = w1[(size_t)u * 33] * w2v[e];
            civs  += civ[e];
        }
        b2v = b2[0];
    }

    __syncthreads();

    const f32x4 z4 = {0.0f, 0.0f, 0.0f, 0.0f};

    // ---- main loop: A computes step t; B finishes step t-1 ----
    for (int t = 0; t <= Ln; ++t) {
        if (w == 0 && t < Ln) {
            const float2 tmv = tm[c][t];
            const float tau = tmv.x;
            const float m   = tmv.y;

            f16x8 bf;
#pragma unroll
            for (int e = 0; e < 8; ++e) bf[e] = (_Float16)hreg[e];

            f32x4 acc[8];
#pragma unroll
            for (int T = 0; T < 8; ++T)
                acc[T] = __builtin_amdgcn_mfma_f32_16x16x32_f16(Af[T], bf, z4, 0, 0, 0);

            // r,z sigmoids (8-wide levels)
            float pr[8], pz[8], er[8], ez[8], rg[8], zg[8];
#pragma unroll
            for (int e = 0; e < 8; ++e) {
                pr[e] = acc[(e >> 2)][e & 3]     + fmaf(tau, wrA[e], wrB[e]);
                pz[e] = acc[2 + (e >> 2)][e & 3] + fmaf(tau, wzA[e], wzB[e]);
            }
#pragma unroll
            for (int e = 0; e < 8; ++e) er[e] = __expf(-pr[e]);
#pragma unroll
            for (int e = 0; e < 8; ++e) ez[e] = __expf(-pz[e]);
#pragma unroll
            for (int e = 0; e < 8; ++e) rg[e] = __frcp_rn(1.0f + er[e]);
#pragma unroll
            for (int e = 0; e < 8; ++e) zg[e] = __frcp_rn(1.0f + ez[e]);

            // intensity pre-acts -> pbuf (off critical path)
            f16x8 pv;
#pragma unroll
            for (int e = 0; e < 8; ++e)
                pv[e] = (_Float16)(acc[6 + (e >> 2)][e & 3] + fmaf(tau, wpA[e], wpB[e]));
            *(f16x8*)&pbuf[t & 1][c][8 * g] = pv;

            // n gate + h update
            float npe[8], nex[8];
#pragma unroll
            for (int e = 0; e < 8; ++e)
                npe[e] = fmaf(tau, wnA[e], wnB[e])
                       + rg[e] * (acc[4 + (e >> 2)][e & 3] + wnC[e]);
#pragma unroll
            for (int e = 0; e < 8; ++e)
                nex[e] = __expf(2.0f * fminf(npe[e], 15.0f));
#pragma unroll
            for (int e = 0; e < 8; ++e) {
                const float nn  = __fdividef(nex[e] - 1.0f, nex[e] + 1.0f);
                const float hn2 = fmaf(zg[e], hreg[e] - nn, nn);
                hreg[e] = fmaf(m, hn2 - hreg[e], hreg[e]);
            }
        } else if (w == 1 && t > 0) {
            const int tp = t - 1;
            const f16x8 pv = *(const f16x8*)&pbuf[tp & 1][c][8 * g];
            float aex[8];
#pragma unroll
            for (int e = 0; e < 8; ++e)
                aex[e] = __expf(2.0f * fminf((float)pv[e], 15.0f));
            float v1p = 0.0f, v2p = civs;
#pragma unroll
            for (int e = 0; e < 8; ++e) {
                const float a = __fdividef(aex[e] - 1.0f, aex[e] + 1.0f);
                v1p = fmaf(a, w2v[e], v1p);
                v2p = fmaf(a * a, -civ[e], v2p);
            }
            v1p += __shfl_xor(v1p, 16, 64);
            v1p += __shfl_xor(v1p, 32, 64);
            v2p += __shfl_xor(v2p, 16, 64);
            v2p += __shfl_xor(v2p, 32, 64);
            if (l < 16) {
                PK2 pk;
                pk.f[0] = (_Float16)(v1p + b2v);
                pk.f[1] = (_Float16)v2p;
                ibuf[l * 520 + tp] = pk.u;
            }
        }
        __syncthreads();
    }

    // ---- phase 2: LL transcendentals over 16 x 512 items, 128 threads ----
    float T = 0.0f, M = 0.0f;
#pragma unroll 4
    for (int it = 0; it < 64; ++it) {
        const int idx = it * 128 + tid;         // cc*512 + tt
        const int cc  = idx >> 9;
        const int tt  = idx & 511;
        PK2 pk; pk.u = ibuf[cc * 520 + tt];
        const float raw = (float)pk.f[0];
        const float v2  = (float)pk.f[1];
        const float mm  = tm[cc][tt].y;
        const float phi  = softplusf_(raw);
        const float dphi = sigmoidf_(raw) * v2;
        const float lam  = softplusf_(dphi) + EPSf;
        T = fmaf(__logf(lam) - phi, mm, T);
        M += mm;
    }
#pragma unroll
    for (int d = 1; d < 64; d <<= 1) {
        T += __shfl_xor(T, d, 64);
        M += __shfl_xor(M, d, 64);
    }
    __shared__ float sT[2], sM[2];
    if (l == 0) { sT[w] = T; sM[w] = M; }
    __syncthreads();
    if (tid == 0) {
        partials[blockIdx.x]             = sT[0] + sT[1];
        partials[gridDim.x + blockIdx.x] = sM[0] + sM[1];
    }
}

__global__ __launch_bounds__(256)
void tpp_final(const float* __restrict__ partials, int nparts,
               float* __restrict__ out)
{
    const int tid = threadIdx.x;
    double T = 0.0, M = 0.0;
    for (int k = tid; k < nparts; k += 256) {
        T += (double)partials[k];
        M += (double)partials[nparts + k];
    }
#pragma unroll
    for (int d = 1; d < 64; d <<= 1) {
        T += __shfl_xor(T, d, 64);
        M += __shfl_xor(M, d, 64);
    }
    __shared__ double sT[4], sM[4];
    const int w = tid >> 6;
    if ((tid & 63) == 0) { sT[w] = T; sM[w] = M; }
    __syncthreads();
    if (tid == 0) {
        const double t2 = sT[0] + sT[1] + sT[2] + sT[3];
        const double m2 = sM[0] + sM[1] + sM[2] + sM[3];
        out[0] = (float)(t2 / (m2 + (double)EPSf));
    }
}

extern "C" void kernel_launch(void* const* d_in, const int* in_sizes, int n_in,
                              void* d_out, int out_size, void* d_ws, size_t ws_size,
                              hipStream_t stream) {
    const float* deltas = (const float*)d_in[0];
    const float* mask   = (const float*)d_in[1];
    const float* w_ih   = (const float*)d_in[2];
    const float* w_hh   = (const float*)d_in[3];
    const float* b_ih   = (const float*)d_in[4];
    const float* b_hh   = (const float*)d_in[5];
    const float* w1     = (const float*)d_in[6];
    const float* b1     = (const float*)d_in[7];
    const float* w2     = (const float*)d_in[8];
    const float* b2     = (const float*)d_in[9];
    float* out = (float*)d_out;
    float* partials = (float*)d_ws;      // 2 * 256 * 4 B

    const int nblocks = Bn / 16;         // 256
    tpp_main<<<nblocks, 128, 0, stream>>>(deltas, mask, w_ih, w_hh, b_ih, b_hh,
                                          w1, b1, w2, b2, partials);
    tpp_final<<<1, 256, 0, stream>>>(partials, nblocks, out);
}

// Round 12
// 554.786 us; speedup vs baseline: 1.0650x; 1.0650x over previous
//
#include <hip/hip_runtime.h>
#include <math.h>

// NeuralTPP: B=4096, L=512, H=HH=32 — register-resident recurrence,
// chunk-amortized synchronization.
// Block = 128 thr = 2 waves, 16 seqs/block, 256 blocks (1 block/CU).
// Wave A: ENTIRE GRU recurrence in registers (h = next B-fragment, R5
// permutation, zero repack). Per step: 8 MFMA + r/z/n chains. Its only
// LDS ops: prefetched tm read + fire-and-forget pbuf write.
// Wave B: intensity tail, processes the PREVIOUS 16-step chunk from the
// double-buffered pbuf ring; unroll-4 across independent steps.
// ONE barrier per 16 steps (33 total vs 513 in R10).

constexpr int Bn = 4096;
constexpr int Ln = 512;
constexpr float EPSf = 1e-8f;

typedef _Float16 f16x8 __attribute__((ext_vector_type(8)));
typedef float    f32x4 __attribute__((ext_vector_type(4)));

__device__ __forceinline__ float sigmoidf_(float x) {
    return __fdividef(1.0f, 1.0f + __expf(-x));
}
__device__ __forceinline__ float softplusf_(float x) {
    return fmaxf(x, 0.0f) + __logf(1.0f + __expf(-fabsf(x)));
}

union PK2 { _Float16 f[2]; unsigned u; };

__global__ __launch_bounds__(128, 1)
void tpp_main(const float* __restrict__ deltas,
              const float* __restrict__ mask,
              const float* __restrict__ w_ih,
              const float* __restrict__ w_hh,
              const float* __restrict__ b_ih,
              const float* __restrict__ b_hh,
              const float* __restrict__ w1,
              const float* __restrict__ b1,
              const float* __restrict__ w2,
              const float* __restrict__ b2,
              float* __restrict__ partials)   // [2 * gridDim.x]
{
    const int tid = threadIdx.x;
    const int w   = tid >> 6;            // 0 = recurrence wave A, 1 = intensity wave B
    const int l   = tid & 63;
    const int c   = l & 15;              // batch column / A-tile row
    const int g   = l >> 4;              // k-group & C row-group
    const int b0  = blockIdx.x * 16;

    __shared__ float2   tm[16][514];                        // (tau,mask) 65.8 KB
    __shared__ unsigned ibuf[16 * 520];                     // (raw,v2)   33.3 KB
    __shared__ __align__(16) _Float16 pbuf[2][16][16][40];  // p ring     40 KB

    // ---- stage (tau, mask) into LDS ----
    for (int q = tid; q < 16 * 128; q += 128) {
        const int cc = q >> 7;
        const int t4 = (q & 127) << 2;
        const float4 dv = *(const float4*)(deltas + (size_t)(b0 + cc) * Ln + t4);
        const float4 mv = *(const float4*)(mask   + (size_t)(b0 + cc) * Ln + t4);
        tm[cc][t4 + 0] = make_float2(dv.x, mv.x);
        tm[cc][t4 + 1] = make_float2(dv.y, mv.y);
        tm[cc][t4 + 2] = make_float2(dv.z, mv.z);
        tm[cc][t4 + 3] = make_float2(dv.w, mv.w);
    }

    // ---- per-wave constants ----
    f16x8 Af[8];                                   // wave A: all 8 A-tiles
    float wrA[8], wrB[8], wzA[8], wzB[8];
    float wnA[8], wnB[8], wnC[8], wpA[8], wpB[8];  // wave A per-unit scalars
    float w2v[8], civ[8], civs = 0.0f, b2v = 0.0f; // wave B scalars
    float hreg[8];

    if (w == 0) {
        const int ub = 8 * (c >> 2) + (c & 3);
        const int j0 = 8 * g;
#pragma unroll
        for (int T = 0; T < 8; ++T) {
            const int G = T >> 1, p = T & 1;
            const int up = ub + 4 * p;
            const float* src =
                (G == 0) ? (w_hh + (size_t)up * 32 + j0) :
                (G == 1) ? (w_hh + (size_t)(32 + up) * 32 + j0) :
                (G == 2) ? (w_hh + (size_t)(64 + up) * 32 + j0) :
                           (w1   + (size_t)up * 33 + 1 + j0);
#pragma unroll
            for (int e = 0; e < 8; ++e) Af[T][e] = (_Float16)src[e];
        }
#pragma unroll
        for (int e = 0; e < 8; ++e) {
            const int u = 8 * g + e;
            wrA[e] = w_ih[u];
            wrB[e] = b_ih[u] + b_hh[u];
            wzA[e] = w_ih[32 + u];
            wzB[e] = b_ih[32 + u] + b_hh[32 + u];
            wnA[e] = w_ih[64 + u];
            wnB[e] = b_ih[64 + u];
            wnC[e] = b_hh[64 + u];
            wpA[e] = w1[(size_t)u * 33];
            wpB[e] = b1[u];
            hreg[e] = 0.0f;
        }
    } else {
#pragma unroll
        for (int e = 0; e < 8; ++e) {
            const int u = 8 * g + e;
            w2v[e] = w2[u];
            civ[e] = w1[(size_t)u * 33] * w2v[e];
            civs  += civ[e];
        }
        b2v = b2[0];
    }

    __syncthreads();

    const f32x4 z4 = {0.0f, 0.0f, 0.0f, 0.0f};
    constexpr int NC = Ln / 16;          // 32 chunks

    for (int chunk = 0; chunk <= NC; ++chunk) {
        if (w == 0 && chunk < NC) {
            const int tbase = chunk * 16;
            float2 tmv = tm[c][tbase];
#pragma unroll 2
            for (int s = 0; s < 16; ++s) {
                const int t = tbase + s;
                const float2 tmn = tm[c][(t + 1 < Ln) ? (t + 1) : t];  // prefetch
                const float tau = tmv.x;
                const float m   = tmv.y;

                f16x8 bf;
#pragma unroll
                for (int e = 0; e < 8; ++e) bf[e] = (_Float16)hreg[e];

                f32x4 acc[8];
#pragma unroll
                for (int T = 0; T < 8; ++T)
                    acc[T] = __builtin_amdgcn_mfma_f32_16x16x32_f16(Af[T], bf, z4, 0, 0, 0);

                // r,z sigmoids (8-wide levels)
                float pr[8], pz[8], er[8], ez[8], rg[8], zg[8];
#pragma unroll
                for (int e = 0; e < 8; ++e) {
                    pr[e] = acc[(e >> 2)][e & 3]     + fmaf(tau, wrA[e], wrB[e]);
                    pz[e] = acc[2 + (e >> 2)][e & 3] + fmaf(tau, wzA[e], wzB[e]);
                }
#pragma unroll
                for (int e = 0; e < 8; ++e) er[e] = __expf(-pr[e]);
#pragma unroll
                for (int e = 0; e < 8; ++e) ez[e] = __expf(-pz[e]);
#pragma unroll
                for (int e = 0; e < 8; ++e) rg[e] = __frcp_rn(1.0f + er[e]);
#pragma unroll
                for (int e = 0; e < 8; ++e) zg[e] = __frcp_rn(1.0f + ez[e]);

                // intensity pre-acts -> pbuf ring (fire-and-forget)
                f16x8 pv;
#pragma unroll
                for (int e = 0; e < 8; ++e)
                    pv[e] = (_Float16)(acc[6 + (e >> 2)][e & 3] + fmaf(tau, wpA[e], wpB[e]));
                *(f16x8*)&pbuf[chunk & 1][s][c][8 * g] = pv;

                // n gate + h update
                float npe[8], nex[8];
#pragma unroll
                for (int e = 0; e < 8; ++e)
                    npe[e] = fmaf(tau, wnA[e], wnB[e])
                           + rg[e] * (acc[4 + (e >> 2)][e & 3] + wnC[e]);
#pragma unroll
                for (int e = 0; e < 8; ++e)
                    nex[e] = __expf(2.0f * fminf(npe[e], 15.0f));
#pragma unroll
                for (int e = 0; e < 8; ++e) {
                    const float nn  = __fdividef(nex[e] - 1.0f, nex[e] + 1.0f);
                    const float hn2 = fmaf(zg[e], hreg[e] - nn, nn);
                    hreg[e] = fmaf(m, hn2 - hreg[e], hreg[e]);
                }
                tmv = tmn;
            }
        } else if (w == 1 && chunk > 0) {
            const int tbase = (chunk - 1) * 16;
            const int rb    = (chunk - 1) & 1;
#pragma unroll 4
            for (int s = 0; s < 16; ++s) {
                const f16x8 pv = *(const f16x8*)&pbuf[rb][s][c][8 * g];
                float aex[8];
#pragma unroll
                for (int e = 0; e < 8; ++e)
                    aex[e] = __expf(2.0f * fminf((float)pv[e], 15.0f));
                float v1p = 0.0f, v2p = civs;
#pragma unroll
                for (int e = 0; e < 8; ++e) {
                    const float a = __fdividef(aex[e] - 1.0f, aex[e] + 1.0f);
                    v1p = fmaf(a, w2v[e], v1p);
                    v2p = fmaf(a * a, -civ[e], v2p);
                }
                v1p += __shfl_xor(v1p, 16, 64);
                v1p += __shfl_xor(v1p, 32, 64);
                v2p += __shfl_xor(v2p, 16, 64);
                v2p += __shfl_xor(v2p, 32, 64);
                if (l < 16) {
                    PK2 pk;
                    pk.f[0] = (_Float16)(v1p + b2v);
                    pk.f[1] = (_Float16)v2p;
                    ibuf[l * 520 + tbase + s] = pk.u;
                }
            }
        }
        __syncthreads();
    }

    // ---- phase 2: LL transcendentals over 16 x 512 items, 128 threads ----
    float T = 0.0f, M = 0.0f;
#pragma unroll 4
    for (int it = 0; it < 64; ++it) {
        const int idx = it * 128 + tid;         // cc*512 + tt
        const int cc  = idx >> 9;
        const int tt  = idx & 511;
        PK2 pk; pk.u = ibuf[cc * 520 + tt];
        const float raw = (float)pk.f[0];
        const float v2  = (float)pk.f[1];
        const float mm  = tm[cc][tt].y;
        const float phi  = softplusf_(raw);
        const float dphi = sigmoidf_(raw) * v2;
        const float lam  = softplusf_(dphi) + EPSf;
        T = fmaf(__logf(lam) - phi, mm, T);
        M += mm;
    }
#pragma unroll
    for (int d = 1; d < 64; d <<= 1) {
        T += __shfl_xor(T, d, 64);
        M += __shfl_xor(M, d, 64);
    }
    __shared__ float sT[2], sM[2];
    if (l == 0) { sT[w] = T; sM[w] = M; }
    __syncthreads();
    if (tid == 0) {
        partials[blockIdx.x]             = sT[0] + sT[1];
        partials[gridDim.x + blockIdx.x] = sM[0] + sM[1];
    }
}

__global__ __launch_bounds__(256)
void tpp_final(const float* __restrict__ partials, int nparts,
               float* __restrict__ out)
{
    const int tid = threadIdx.x;
    double T = 0.0, M = 0.0;
    for (int k = tid; k < nparts; k += 256) {
        T += (double)partials[k];
        M += (double)partials[nparts + k];
    }
#pragma unroll
    for (int d = 1; d < 64; d <<= 1) {
        T += __shfl_xor(T, d, 64);
        M += __shfl_xor(M, d, 64);
    }
    __shared__ double sT[4], sM[4];
    const int w = tid >> 6;
    if ((tid & 63) == 0) { sT[w] = T; sM[w] = M; }
    __syncthreads();
    if (tid == 0) {
        const double t2 = sT[0] + sT[1] + sT[2] + sT[3];
        const double m2 = sM[0] + sM[1] + sM[2] + sM[3];
        out[0] = (float)(t2 / (m2 + (double)EPSf));
    }
}

extern "C" void kernel_launch(void* const* d_in, const int* in_sizes, int n_in,
                              void* d_out, int out_size, void* d_ws, size_t ws_size,
                              hipStream_t stream) {
    const float* deltas = (const float*)d_in[0];
    const float* mask   = (const float*)d_in[1];
    const float* w_ih   = (const float*)d_in[2];
    const float* w_hh   = (const float*)d_in[3];
    const float* b_ih   = (const float*)d_in[4];
    const float* b_hh   = (const float*)d_in[5];
    const float* w1     = (const float*)d_in[6];
    const float* b1     = (const float*)d_in[7];
    const float* w2     = (const float*)d_in[8];
    const float* b2     = (const float*)d_in[9];
    float* out = (float*)d_out;
    float* partials = (float*)d_ws;      // 2 * 256 * 4 B

    const int nblocks = Bn / 16;         // 256
    tpp_main<<<nblocks, 128, 0, stream>>>(deltas, mask, w_ih, w_hh, b_ih, b_hh,
                                          w1, b1, w2, b2, partials);
    tpp_final<<<1, 256, 0, stream>>>(partials, nblocks, out);
}

// Round 13
// 326.083 us; speedup vs baseline: 1.8119x; 1.7014x over previous
//
#include <hip/hip_runtime.h>
#include <math.h>

// NeuralTPP: B=4096, L=512, H=HH=32 — register-resident MFMA recurrence,
// chunk-amortized sync, FORCED 8-wide transcendental ILP via inline asm.
// Evidence: R6/R11 both ran at ~11 cyc/instr (latency-serialized chains);
// compiler re-serializes 8-wide phase arrays no matter the source shape.
// Fix: v_exp_f32 / v_rcp_f32 emitted as 8 back-to-back volatile asms
// (order-pinned, issue at trans throughput), plus ln2 folded into weights
// so every exp is a bare v_exp_f32 (exp2).
// Wave A: full GRU in registers (h = next B-fragment, R5 zero-repack).
// Wave B: intensity tail on previous 16-step chunk (double-buffered pbuf).
// One barrier per 16 steps.

constexpr int Bn = 4096;
constexpr int Ln = 512;
constexpr float EPSf = 1e-8f;
constexpr float LOG2E  = 1.44269504088896f;
constexpr float S2     = 2.0f * LOG2E;        // tanh scale
constexpr float PCLAMP = 15.0f * S2;          // clamp in exp2 domain

typedef _Float16 f16x8 __attribute__((ext_vector_type(8)));
typedef float    f32x4 __attribute__((ext_vector_type(4)));

__device__ __forceinline__ float aexp2(float x) {   // v_exp_f32 = 2^x
    float r;
    asm volatile("v_exp_f32 %0, %1" : "=v"(r) : "v"(x));
    return r;
}
__device__ __forceinline__ float arcp(float x) {    // v_rcp_f32
    float r;
    asm volatile("v_rcp_f32 %0, %1" : "=v"(r) : "v"(x));
    return r;
}

__device__ __forceinline__ float softplusf_(float x) {
    return fmaxf(x, 0.0f) + __logf(1.0f + __expf(-fabsf(x)));
}
__device__ __forceinline__ float sigmoidf_(float x) {
    return __fdividef(1.0f, 1.0f + __expf(-x));
}

union PK2 { _Float16 f[2]; unsigned u; };

__global__ __launch_bounds__(128, 1)
void tpp_main(const float* __restrict__ deltas,
              const float* __restrict__ mask,
              const float* __restrict__ w_ih,
              const float* __restrict__ w_hh,
              const float* __restrict__ b_ih,
              const float* __restrict__ b_hh,
              const float* __restrict__ w1,
              const float* __restrict__ b1,
              const float* __restrict__ w2,
              const float* __restrict__ b2,
              float* __restrict__ partials)   // [2 * gridDim.x]
{
    const int tid = threadIdx.x;
    const int w   = tid >> 6;            // 0 = recurrence wave A, 1 = intensity wave B
    const int l   = tid & 63;
    const int c   = l & 15;              // batch column / A-tile row
    const int g   = l >> 4;              // k-group & C row-group
    const int b0  = blockIdx.x * 16;

    __shared__ float2   tm[16][514];                        // (tau,mask) 65.8 KB
    __shared__ unsigned ibuf[16 * 520];                     // (raw,v2)   33.3 KB
    __shared__ __align__(16) _Float16 pbuf[2][16][16][40];  // p ring     40 KB

    // ---- stage (tau, mask) into LDS ----
    for (int q = tid; q < 16 * 128; q += 128) {
        const int cc = q >> 7;
        const int t4 = (q & 127) << 2;
        const float4 dv = *(const float4*)(deltas + (size_t)(b0 + cc) * Ln + t4);
        const float4 mv = *(const float4*)(mask   + (size_t)(b0 + cc) * Ln + t4);
        tm[cc][t4 + 0] = make_float2(dv.x, mv.x);
        tm[cc][t4 + 1] = make_float2(dv.y, mv.y);
        tm[cc][t4 + 2] = make_float2(dv.z, mv.z);
        tm[cc][t4 + 3] = make_float2(dv.w, mv.w);
    }

    // ---- per-wave constants (pre-scaled; r/z negated) ----
    f16x8 Af[8];                                   // A-tiles (rows pre-scaled)
    float wrAn[8], wrBn[8], wzAn[8], wzBn[8];      // NEGATED, xLOG2E
    float wnA[8], wnB[8], wnC[8];                  // xS2
    float wpA[8], wpB[8];                          // xS2
    float w2v[8], civ[8], civs = 0.0f, b2v = 0.0f; // wave B scalars
    float hreg[8];

    if (w == 0) {
        const int ub = 8 * (c >> 2) + (c & 3);
        const int j0 = 8 * g;
#pragma unroll
        for (int T = 0; T < 8; ++T) {
            const int G = T >> 1, p = T & 1;
            const int up = ub + 4 * p;
            const float sc = (G < 2) ? LOG2E : S2;
            const float* src =
                (G == 0) ? (w_hh + (size_t)up * 32 + j0) :
                (G == 1) ? (w_hh + (size_t)(32 + up) * 32 + j0) :
                (G == 2) ? (w_hh + (size_t)(64 + up) * 32 + j0) :
                           (w1   + (size_t)up * 33 + 1 + j0);
#pragma unroll
            for (int e = 0; e < 8; ++e) Af[T][e] = (_Float16)(src[e] * sc);
        }
#pragma unroll
        for (int e = 0; e < 8; ++e) {
            const int u = 8 * g + e;
            wrAn[e] = -w_ih[u] * LOG2E;
            wrBn[e] = -(b_ih[u] + b_hh[u]) * LOG2E;
            wzAn[e] = -w_ih[32 + u] * LOG2E;
            wzBn[e] = -(b_ih[32 + u] + b_hh[32 + u]) * LOG2E;
            wnA[e]  = w_ih[64 + u] * S2;
            wnB[e]  = b_ih[64 + u] * S2;
            wnC[e]  = b_hh[64 + u] * S2;
            wpA[e]  = w1[(size_t)u * 33] * S2;
            wpB[e]  = b1[u] * S2;
            hreg[e] = 0.0f;
        }
    } else {
#pragma unroll
        for (int e = 0; e < 8; ++e) {
            const int u = 8 * g + e;
            w2v[e] = w2[u];
            civ[e] = w1[(size_t)u * 33] * w2v[e];
            civs  += civ[e];
        }
        b2v = b2[0];
    }

    __syncthreads();

    const f32x4 z4 = {0.0f, 0.0f, 0.0f, 0.0f};
    constexpr int NC = Ln / 16;          // 32 chunks

    for (int chunk = 0; chunk <= NC; ++chunk) {
        if (w == 0 && chunk < NC) {
            const int tbase = chunk * 16;
            float2 tmv = tm[c][tbase];
            for (int s = 0; s < 16; ++s) {
                const int t = tbase + s;
                const float2 tmn = tm[c][(t + 1 < Ln) ? (t + 1) : t];  // prefetch
                const float tau = tmv.x;
                const float m   = tmv.y;

                f16x8 bf;
#pragma unroll
                for (int e = 0; e < 8; ++e) bf[e] = (_Float16)hreg[e];

                f32x4 acc[8];
#pragma unroll
                for (int T = 0; T < 8; ++T)
                    acc[T] = __builtin_amdgcn_mfma_f32_16x16x32_f16(Af[T], bf, z4, 0, 0, 0);

                // ---- phase 1: negated scaled pre-acts for r,z ----
                float prn[8], pzn[8];
#pragma unroll
                for (int e = 0; e < 8; ++e) {
                    prn[e] = fmaf(tau, wrAn[e], wrBn[e]) - acc[(e >> 2)][e & 3];
                    pzn[e] = fmaf(tau, wzAn[e], wzBn[e]) - acc[2 + (e >> 2)][e & 3];
                }
                // ---- phase 2: 16 exp2, order-pinned back-to-back ----
                float er[8], ez[8];
#pragma unroll
                for (int e = 0; e < 8; ++e) er[e] = aexp2(prn[e]);
#pragma unroll
                for (int e = 0; e < 8; ++e) ez[e] = aexp2(pzn[e]);
                // ---- phase 3: 16 rcp ----
                float rg[8], zg[8];
#pragma unroll
                for (int e = 0; e < 8; ++e) rg[e] = arcp(1.0f + er[e]);
#pragma unroll
                for (int e = 0; e < 8; ++e) zg[e] = arcp(1.0f + ez[e]);

                // ---- intensity pre-acts (scaled, clamped) -> pbuf ring ----
                f16x8 pv;
#pragma unroll
                for (int e = 0; e < 8; ++e) {
                    const float p = acc[6 + (e >> 2)][e & 3] + fmaf(tau, wpA[e], wpB[e]);
                    pv[e] = (_Float16)fminf(p, PCLAMP);
                }
                *(f16x8*)&pbuf[chunk & 1][s][c][8 * g] = pv;

                // ---- n gate ----
                float npe[8];
#pragma unroll
                for (int e = 0; e < 8; ++e)
                    npe[e] = fminf(fmaf(tau, wnA[e], wnB[e])
                           + rg[e] * (acc[4 + (e >> 2)][e & 3] + wnC[e]), PCLAMP);
                float nex[8];
#pragma unroll
                for (int e = 0; e < 8; ++e) nex[e] = aexp2(npe[e]);
                float nrc[8];
#pragma unroll
                for (int e = 0; e < 8; ++e) nrc[e] = arcp(1.0f + nex[e]);

                // ---- h update: nn = 1 - 2*nrc ; h += m*(nn + zg*(h-nn) - h) ----
#pragma unroll
                for (int e = 0; e < 8; ++e) {
                    const float nn  = fmaf(-2.0f, nrc[e], 1.0f);
                    const float hn2 = fmaf(zg[e], hreg[e] - nn, nn);
                    hreg[e] = fmaf(m, hn2 - hreg[e], hreg[e]);
                }
                tmv = tmn;
            }
        } else if (w == 1 && chunk > 0) {
            const int tbase = (chunk - 1) * 16;
            const int rb    = (chunk - 1) & 1;
#pragma unroll 2
            for (int s = 0; s < 16; ++s) {
                const f16x8 pv = *(const f16x8*)&pbuf[rb][s][c][8 * g];
                float aex[8];
#pragma unroll
                for (int e = 0; e < 8; ++e) aex[e] = aexp2((float)pv[e]);
                float arc[8];
#pragma unroll
                for (int e = 0; e < 8; ++e) arc[e] = arcp(1.0f + aex[e]);
                float v1p = 0.0f, v2p = civs;
#pragma unroll
                for (int e = 0; e < 8; ++e) {
                    const float a = fmaf(-2.0f, arc[e], 1.0f);
                    v1p = fmaf(a, w2v[e], v1p);
                    v2p = fmaf(a * a, -civ[e], v2p);
                }
                v1p += __shfl_xor(v1p, 16, 64);
                v1p += __shfl_xor(v1p, 32, 64);
                v2p += __shfl_xor(v2p, 16, 64);
                v2p += __shfl_xor(v2p, 32, 64);
                if (l < 16) {
                    PK2 pk;
                    pk.f[0] = (_Float16)(v1p + b2v);
                    pk.f[1] = (_Float16)v2p;
                    ibuf[l * 520 + tbase + s] = pk.u;
                }
            }
        }
        __syncthreads();
    }

    // ---- phase 2: LL transcendentals over 16 x 512 items, 128 threads ----
    float T = 0.0f, M = 0.0f;
#pragma unroll 4
    for (int it = 0; it < 64; ++it) {
        const int idx = it * 128 + tid;         // cc*512 + tt
        const int cc  = idx >> 9;
        const int tt  = idx & 511;
        PK2 pk; pk.u = ibuf[cc * 520 + tt];
        const float raw = (float)pk.f[0];
        const float v2  = (float)pk.f[1];
        const float mm  = tm[cc][tt].y;
        const float phi  = softplusf_(raw);
        const float dphi = sigmoidf_(raw) * v2;
        const float lam  = softplusf_(dphi) + EPSf;
        T = fmaf(__logf(lam) - phi, mm, T);
        M += mm;
    }
#pragma unroll
    for (int d = 1; d < 64; d <<= 1) {
        T += __shfl_xor(T, d, 64);
        M += __shfl_xor(M, d, 64);
    }
    __shared__ float sT[2], sM[2];
    if (l == 0) { sT[w] = T; sM[w] = M; }
    __syncthreads();
    if (tid == 0) {
        partials[blockIdx.x]             = sT[0] + sT[1];
        partials[gridDim.x + blockIdx.x] = sM[0] + sM[1];
    }
}

__global__ __launch_bounds__(256)
void tpp_final(const float* __restrict__ partials, int nparts,
               float* __restrict__ out)
{
    const int tid = threadIdx.x;
    double T = 0.0, M = 0.0;
    for (int k = tid; k < nparts; k += 256) {
        T += (double)partials[k];
        M += (double)partials[nparts + k];
    }
#pragma unroll
    for (int d = 1; d < 64; d <<= 1) {
        T += __shfl_xor(T, d, 64);
        M += __shfl_xor(M, d, 64);
    }
    __shared__ double sT[4], sM[4];
    const int w = tid >> 6;
    if ((tid & 63) == 0) { sT[w] = T; sM[w] = M; }
    __syncthreads();
    if (tid == 0) {
        const double t2 = sT[0] + sT[1] + sT[2] + sT[3];
        const double m2 = sM[0] + sM[1] + sM[2] + sM[3];
        out[0] = (float)(t2 / (m2 + (double)EPSf));
    }
}

extern "C" void kernel_launch(void* const* d_in, const int* in_sizes, int n_in,
                              void* d_out, int out_size, void* d_ws, size_t ws_size,
                              hipStream_t stream) {
    const float* deltas = (const float*)d_in[0];
    const float* mask   = (const float*)d_in[1];
    const float* w_ih   = (const float*)d_in[2];
    const float* w_hh   = (const float*)d_in[3];
    const float* b_ih   = (const float*)d_in[4];
    const float* b_hh   = (const float*)d_in[5];
    const float* w1     = (const float*)d_in[6];
    const float* b1     = (const float*)d_in[7];
    const float* w2     = (const float*)d_in[8];
    const float* b2     = (const float*)d_in[9];
    float* out = (float*)d_out;
    float* partials = (float*)d_ws;      // 2 * 256 * 4 B

    const int nblocks = Bn / 16;         // 256
    tpp_main<<<nblocks, 128, 0, stream>>>(deltas, mask, w_ih, w_hh, b_ih, b_hh,
                                          w1, b1, w2, b2, partials);
    tpp_final<<<1, 256, 0, stream>>>(partials, nblocks, out);
}

// Round 15
// 267.134 us; speedup vs baseline: 2.2117x; 1.2207x over previous
//
#include <hip/hip_runtime.h>
#include <math.h>

// NeuralTPP: B=4096, L=512, H=HH=32 — register-resident MFMA recurrence,
// chunk-amortized sync, asm-forced trans ILP (R12, 333us), wave A slimmed:
// p-gate offloaded to wave B (via f16 h ring), biases folded into MFMA
// C-operand (prn = acc directly), algebraic h-update, cvt_pkrtz pack.
// Wave A (~170 instr/step): 6 MFMA + r/z/n chains + h-update. No VMEM, no
// barrier on critical path (1 barrier / 16 steps).
// Wave B: p-MFMA + intensity tail on previous chunk's h ring; fully hidden.
// (R13 fix: cvt_pkrtz returns __fp16x2 — element-assign instead of init.)

constexpr int Bn = 4096;
constexpr int Ln = 512;
constexpr float EPSf = 1e-8f;
constexpr float LOG2E  = 1.44269504088896f;
constexpr float S2     = 2.0f * LOG2E;        // tanh scale
constexpr float PCLAMP = 15.0f * S2;          // clamp in exp2 domain

typedef _Float16 f16x8 __attribute__((ext_vector_type(8)));
typedef float    f32x4 __attribute__((ext_vector_type(4)));

__device__ __forceinline__ float aexp2(float x) {   // v_exp_f32 = 2^x
    float r;
    asm volatile("v_exp_f32 %0, %1" : "=v"(r) : "v"(x));
    return r;
}
__device__ __forceinline__ float arcp(float x) {    // v_rcp_f32
    float r;
    asm volatile("v_rcp_f32 %0, %1" : "=v"(r) : "v"(x));
    return r;
}

__device__ __forceinline__ float softplusf_(float x) {
    return fmaxf(x, 0.0f) + __logf(1.0f + __expf(-fabsf(x)));
}
__device__ __forceinline__ float sigmoidf_(float x) {
    return __fdividef(1.0f, 1.0f + __expf(-x));
}

union PK2 { _Float16 f[2]; unsigned u; };

__global__ __launch_bounds__(128, 1)
void tpp_main(const float* __restrict__ deltas,
              const float* __restrict__ mask,
              const float* __restrict__ w_ih,
              const float* __restrict__ w_hh,
              const float* __restrict__ b_ih,
              const float* __restrict__ b_hh,
              const float* __restrict__ w1,
              const float* __restrict__ b1,
              const float* __restrict__ w2,
              const float* __restrict__ b2,
              float* __restrict__ partials)   // [2 * gridDim.x]
{
    const int tid = threadIdx.x;
    const int w   = tid >> 6;            // 0 = recurrence wave A, 1 = tail wave B
    const int l   = tid & 63;
    const int c   = l & 15;              // batch column / A-tile row
    const int g   = l >> 4;              // k-group & C row-group
    const int b0  = blockIdx.x * 16;

    __shared__ float2   tm[16][514];                 // (tau,mask)    65.8 KB
    __shared__ unsigned ibuf[16 * 520];              // (raw,v2)      33.3 KB
    __shared__ f16x8    bfbuf[2][16][16][5];         // h ring (pad5) 40 KB

    // ---- stage (tau, mask) into LDS ----
    for (int q = tid; q < 16 * 128; q += 128) {
        const int cc = q >> 7;
        const int t4 = (q & 127) << 2;
        const float4 dv = *(const float4*)(deltas + (size_t)(b0 + cc) * Ln + t4);
        const float4 mv = *(const float4*)(mask   + (size_t)(b0 + cc) * Ln + t4);
        tm[cc][t4 + 0] = make_float2(dv.x, mv.x);
        tm[cc][t4 + 1] = make_float2(dv.y, mv.y);
        tm[cc][t4 + 2] = make_float2(dv.z, mv.z);
        tm[cc][t4 + 3] = make_float2(dv.w, mv.w);
    }

    // ---- per-wave constants ----
    f16x8 Af[6];                                   // A: r0,r1,z0,z1,n0,n1
    float wrAn[8], wrBn[8], wzAn[8], wzBn[8];      // r/z: NEGATED x LOG2E
    float wnA[8], wnB[8];                          // n: x S2
    f32x4 Cn0 = {}, Cn1 = {};                      // n C-init (S2*bhh_n), const
    float hreg[8];
    f16x8 Afp[2];                                  // B: p0,p1 tiles (x S2)
    float wpA[8], wpB[8];                          // B: p C-init scalars
    float w2v[8], civ[8], civs = 0.0f, b2v = 0.0f; // B scalars

    const int ub = 8 * (c >> 2) + (c & 3);
    const int j0 = 8 * g;
    if (w == 0) {
#pragma unroll
        for (int T = 0; T < 6; ++T) {
            const int G = T >> 1, p = T & 1;
            const int up = ub + 4 * p;
            const float sc = (G < 2) ? -LOG2E : S2;
            const float* src =
                (G == 0) ? (w_hh + (size_t)up * 32 + j0) :
                (G == 1) ? (w_hh + (size_t)(32 + up) * 32 + j0) :
                           (w_hh + (size_t)(64 + up) * 32 + j0);
#pragma unroll
            for (int e = 0; e < 8; ++e) Af[T][e] = (_Float16)(src[e] * sc);
        }
#pragma unroll
        for (int e = 0; e < 8; ++e) {
            const int u = 8 * g + e;
            wrAn[e] = -w_ih[u] * LOG2E;
            wrBn[e] = -(b_ih[u] + b_hh[u]) * LOG2E;
            wzAn[e] = -w_ih[32 + u] * LOG2E;
            wzBn[e] = -(b_ih[32 + u] + b_hh[32 + u]) * LOG2E;
            wnA[e]  = w_ih[64 + u] * S2;
            wnB[e]  = b_ih[64 + u] * S2;
            hreg[e] = 0.0f;
        }
#pragma unroll
        for (int d = 0; d < 4; ++d) {
            Cn0[d] = b_hh[64 + 8 * g + d] * S2;
            Cn1[d] = b_hh[64 + 8 * g + 4 + d] * S2;
        }
    } else {
#pragma unroll
        for (int p = 0; p < 2; ++p) {
            const int up = ub + 4 * p;
            const float* src = w1 + (size_t)up * 33 + 1 + j0;
#pragma unroll
            for (int e = 0; e < 8; ++e) Afp[p][e] = (_Float16)(src[e] * S2);
        }
#pragma unroll
        for (int e = 0; e < 8; ++e) {
            const int u = 8 * g + e;
            wpA[e] = w1[(size_t)u * 33] * S2;
            wpB[e] = b1[u] * S2;
            w2v[e] = w2[u];
            civ[e] = w1[(size_t)u * 33] * w2v[e];
            civs  += civ[e];
        }
        b2v = b2[0];
    }

    __syncthreads();

    constexpr int NC = Ln / 16;          // 32 chunks

    for (int chunk = 0; chunk <= NC; ++chunk) {
        if (w == 0 && chunk < NC) {
            const int tbase = chunk * 16;
            float2 tmv = tm[c][tbase];
            for (int s = 0; s < 16; ++s) {
                const int t = tbase + s;
                const float2 tmn = tm[c][(t + 1 < Ln) ? (t + 1) : t];  // prefetch
                const float tau = tmv.x;
                const float m   = tmv.y;

                // ---- C-operands: biases folded in (prn = acc directly) ----
                f32x4 Cr0, Cr1, Cz0, Cz1;
#pragma unroll
                for (int d = 0; d < 4; ++d) {
                    Cr0[d] = fmaf(tau, wrAn[d],     wrBn[d]);
                    Cr1[d] = fmaf(tau, wrAn[4 + d], wrBn[4 + d]);
                    Cz0[d] = fmaf(tau, wzAn[d],     wzBn[d]);
                    Cz1[d] = fmaf(tau, wzAn[4 + d], wzBn[4 + d]);
                }

                // ---- pack h -> f16 B-fragment (cvt_pkrtz) ----
                f16x8 bf;
#pragma unroll
                for (int e2 = 0; e2 < 4; ++e2) {
                    const auto pp = __builtin_amdgcn_cvt_pkrtz(hreg[2 * e2], hreg[2 * e2 + 1]);
                    bf[2 * e2]     = (_Float16)pp[0];
                    bf[2 * e2 + 1] = (_Float16)pp[1];
                }
                bfbuf[chunk & 1][s][c][g] = bf;     // for wave B (fire-and-forget)

                // ---- 6 MFMAs: r,z negated-scaled; n scaled ----
                f32x4 ar0 = __builtin_amdgcn_mfma_f32_16x16x32_f16(Af[0], bf, Cr0, 0, 0, 0);
                f32x4 ar1 = __builtin_amdgcn_mfma_f32_16x16x32_f16(Af[1], bf, Cr1, 0, 0, 0);
                f32x4 az0 = __builtin_amdgcn_mfma_f32_16x16x32_f16(Af[2], bf, Cz0, 0, 0, 0);
                f32x4 az1 = __builtin_amdgcn_mfma_f32_16x16x32_f16(Af[3], bf, Cz1, 0, 0, 0);
                f32x4 an0 = __builtin_amdgcn_mfma_f32_16x16x32_f16(Af[4], bf, Cn0, 0, 0, 0);
                f32x4 an1 = __builtin_amdgcn_mfma_f32_16x16x32_f16(Af[5], bf, Cn1, 0, 0, 0);

                // n pre-act base (independent of MFMA results)
                float nbase[8];
#pragma unroll
                for (int e = 0; e < 8; ++e) nbase[e] = fmaf(tau, wnA[e], wnB[e]);

                // ---- r,z: 16 exp2 + 16 rcp, order-pinned ----
                float er[8], ez[8];
#pragma unroll
                for (int d = 0; d < 4; ++d) er[d]     = aexp2(ar0[d]);
#pragma unroll
                for (int d = 0; d < 4; ++d) er[4 + d] = aexp2(ar1[d]);
#pragma unroll
                for (int d = 0; d < 4; ++d) ez[d]     = aexp2(az0[d]);
#pragma unroll
                for (int d = 0; d < 4; ++d) ez[4 + d] = aexp2(az1[d]);
                float rg[8], zg[8];
#pragma unroll
                for (int e = 0; e < 8; ++e) rg[e] = arcp(1.0f + er[e]);
#pragma unroll
                for (int e = 0; e < 8; ++e) zg[e] = arcp(1.0f + ez[e]);

                // ---- n gate ----
                float npe[8];
#pragma unroll
                for (int e = 0; e < 8; ++e) {
                    const float accn = (e < 4) ? an0[e] : an1[e - 4];
                    npe[e] = fminf(fmaf(rg[e], accn, nbase[e]), PCLAMP);
                }
                float nex[8];
#pragma unroll
                for (int e = 0; e < 8; ++e) nex[e] = aexp2(npe[e]);
                float nrc[8];
#pragma unroll
                for (int e = 0; e < 8; ++e) nrc[e] = arcp(1.0f + nex[e]);

                // ---- h update: h += m*(1-z)*(n - h) ----
#pragma unroll
                for (int e = 0; e < 8; ++e) {
                    const float nn = fmaf(-2.0f, nrc[e], 1.0f);
                    const float q  = fmaf(-zg[e], m, m);       // m*(1-z)
                    hreg[e] = fmaf(q, nn - hreg[e], hreg[e]);
                }
                tmv = tmn;
            }
        } else if (w == 1 && chunk > 0) {
            const int tbase = (chunk - 1) * 16;
            const int rb    = (chunk - 1) & 1;
#pragma unroll 2
            for (int s = 0; s < 16; ++s) {
                const f16x8 bfv = bfbuf[rb][s][c][g];
                const float tau = tm[c][tbase + s].x;
                f32x4 Cp0, Cp1;
#pragma unroll
                for (int d = 0; d < 4; ++d) {
                    Cp0[d] = fmaf(tau, wpA[d],     wpB[d]);
                    Cp1[d] = fmaf(tau, wpA[4 + d], wpB[4 + d]);
                }
                const f32x4 a0 = __builtin_amdgcn_mfma_f32_16x16x32_f16(Afp[0], bfv, Cp0, 0, 0, 0);
                const f32x4 a1 = __builtin_amdgcn_mfma_f32_16x16x32_f16(Afp[1], bfv, Cp1, 0, 0, 0);
                float aex[8];
#pragma unroll
                for (int e = 0; e < 8; ++e) {
                    const float pp = fminf((e < 4) ? a0[e] : a1[e - 4], PCLAMP);
                    aex[e] = aexp2(pp);
                }
                float arc[8];
#pragma unroll
                for (int e = 0; e < 8; ++e) arc[e] = arcp(1.0f + aex[e]);
                float v1p = 0.0f, v2p = civs;
#pragma unroll
                for (int e = 0; e < 8; ++e) {
                    const float a = fmaf(-2.0f, arc[e], 1.0f);
                    v1p = fmaf(a, w2v[e], v1p);
                    v2p = fmaf(a * a, -civ[e], v2p);
                }
                v1p += __shfl_xor(v1p, 16, 64);
                v1p += __shfl_xor(v1p, 32, 64);
                v2p += __shfl_xor(v2p, 16, 64);
                v2p += __shfl_xor(v2p, 32, 64);
                if (l < 16) {
                    PK2 pk;
                    pk.f[0] = (_Float16)(v1p + b2v);
                    pk.f[1] = (_Float16)v2p;
                    ibuf[l * 520 + tbase + s] = pk.u;
                }
            }
        }
        __syncthreads();
    }

    // ---- phase 2: LL transcendentals over 16 x 512 items, 128 threads ----
    float T = 0.0f, M = 0.0f;
#pragma unroll 4
    for (int it = 0; it < 64; ++it) {
        const int idx = it * 128 + tid;         // cc*512 + tt
        const int cc  = idx >> 9;
        const int tt  = idx & 511;
        PK2 pk; pk.u = ibuf[cc * 520 + tt];
        const float raw = (float)pk.f[0];
        const float v2  = (float)pk.f[1];
        const float mm  = tm[cc][tt].y;
        const float phi  = softplusf_(raw);
        const float dphi = sigmoidf_(raw) * v2;
        const float lam  = softplusf_(dphi) + EPSf;
        T = fmaf(__logf(lam) - phi, mm, T);
        M += mm;
    }
#pragma unroll
    for (int d = 1; d < 64; d <<= 1) {
        T += __shfl_xor(T, d, 64);
        M += __shfl_xor(M, d, 64);
    }
    __shared__ float sT[2], sM[2];
    if (l == 0) { sT[w] = T; sM[w] = M; }
    __syncthreads();
    if (tid == 0) {
        partials[blockIdx.x]             = sT[0] + sT[1];
        partials[gridDim.x + blockIdx.x] = sM[0] + sM[1];
    }
}

__global__ __launch_bounds__(256)
void tpp_final(const float* __restrict__ partials, int nparts,
               float* __restrict__ out)
{
    const int tid = threadIdx.x;
    double T = 0.0, M = 0.0;
    for (int k = tid; k < nparts; k += 256) {
        T += (double)partials[k];
        M += (double)partials[nparts + k];
    }
#pragma unroll
    for (int d = 1; d < 64; d <<= 1) {
        T += __shfl_xor(T, d, 64);
        M += __shfl_xor(M, d, 64);
    }
    __shared__ double sT[4], sM[4];
    const int w = tid >> 6;
    if ((tid & 63) == 0) { sT[w] = T; sM[w] = M; }
    __syncthreads();
    if (tid == 0) {
        const double t2 = sT[0] + sT[1] + sT[2] + sT[3];
        const double m2 = sM[0] + sM[1] + sM[2] + sM[3];
        out[0] = (float)(t2 / (m2 + (double)EPSf));
    }
}

extern "C" void kernel_launch(void* const* d_in, const int* in_sizes, int n_in,
                              void* d_out, int out_size, void* d_ws, size_t ws_size,
                              hipStream_t stream) {
    const float* deltas = (const float*)d_in[0];
    const float* mask   = (const float*)d_in[1];
    const float* w_ih   = (const float*)d_in[2];
    const float* w_hh   = (const float*)d_in[3];
    const float* b_ih   = (const float*)d_in[4];
    const float* b_hh   = (const float*)d_in[5];
    const float* w1     = (const float*)d_in[6];
    const float* b1     = (const float*)d_in[7];
    const float* w2     = (const float*)d_in[8];
    const float* b2     = (const float*)d_in[9];
    float* out = (float*)d_out;
    float* partials = (float*)d_ws;      // 2 * 256 * 4 B

    const int nblocks = Bn / 16;         // 256
    tpp_main<<<nblocks, 128, 0, stream>>>(deltas, mask, w_ih, w_hh, b_ih, b_hh,
                                          w1, b1, w2, b2, partials);
    tpp_final<<<1, 256, 0, stream>>>(partials, nblocks, out);
}

// Round 16
// 252.819 us; speedup vs baseline: 2.3369x; 1.0566x over previous
//
#include <hip/hip_runtime.h>
#include <math.h>

// NeuralTPP: B=4096, L=512, H=HH=32 — register-resident MFMA recurrence.
// R15: trans-count cuts + MFMA-shadow fill on the R14 skeleton (274us).
//  - batched r/z rcp: inv=rcp((1+er)(1+ez)); rg=inv*(1+ez); zg=inv*(1+er)
//    (8 rcp instead of 16; bounded pre-acts -> no inf risk)
//  - clamps dropped (|npe| <= ~17 bounded; exp2 cannot overflow)
//  - loop-carried MFMA C-operands: next step's C (16 fma) + nbase (8 fma)
//    computed in the MFMA->exp2 latency bubble from prefetched tau.
// Wave A: 6 MFMA + 24 exp2/8+8 rcp + VALU; no VMEM, 1 barrier/16 steps.
// Wave B: p-MFMA + intensity tail on previous chunk's h ring; hidden.

constexpr int Bn = 4096;
constexpr int Ln = 512;
constexpr float EPSf = 1e-8f;
constexpr float LOG2E  = 1.44269504088896f;
constexpr float S2     = 2.0f * LOG2E;        // tanh scale

typedef _Float16 f16x8 __attribute__((ext_vector_type(8)));
typedef float    f32x4 __attribute__((ext_vector_type(4)));

__device__ __forceinline__ float aexp2(float x) {   // v_exp_f32 = 2^x
    float r;
    asm volatile("v_exp_f32 %0, %1" : "=v"(r) : "v"(x));
    return r;
}
__device__ __forceinline__ float arcp(float x) {    // v_rcp_f32
    float r;
    asm volatile("v_rcp_f32 %0, %1" : "=v"(r) : "v"(x));
    return r;
}

__device__ __forceinline__ float softplusf_(float x) {
    return fmaxf(x, 0.0f) + __logf(1.0f + __expf(-fabsf(x)));
}
__device__ __forceinline__ float sigmoidf_(float x) {
    return __fdividef(1.0f, 1.0f + __expf(-x));
}

union PK2 { _Float16 f[2]; unsigned u; };

__global__ __launch_bounds__(128, 1)
void tpp_main(const float* __restrict__ deltas,
              const float* __restrict__ mask,
              const float* __restrict__ w_ih,
              const float* __restrict__ w_hh,
              const float* __restrict__ b_ih,
              const float* __restrict__ b_hh,
              const float* __restrict__ w1,
              const float* __restrict__ b1,
              const float* __restrict__ w2,
              const float* __restrict__ b2,
              float* __restrict__ partials)   // [2 * gridDim.x]
{
    const int tid = threadIdx.x;
    const int w   = tid >> 6;            // 0 = recurrence wave A, 1 = tail wave B
    const int l   = tid & 63;
    const int c   = l & 15;              // batch column / A-tile row
    const int g   = l >> 4;              // k-group & C row-group
    const int b0  = blockIdx.x * 16;

    __shared__ float2   tm[16][514];                 // (tau,mask)    65.8 KB
    __shared__ unsigned ibuf[16 * 520];              // (raw,v2)      33.3 KB
    __shared__ f16x8    bfbuf[2][16][16][5];         // h ring (pad5) 40 KB

    // ---- stage (tau, mask) into LDS ----
    for (int q = tid; q < 16 * 128; q += 128) {
        const int cc = q >> 7;
        const int t4 = (q & 127) << 2;
        const float4 dv = *(const float4*)(deltas + (size_t)(b0 + cc) * Ln + t4);
        const float4 mv = *(const float4*)(mask   + (size_t)(b0 + cc) * Ln + t4);
        tm[cc][t4 + 0] = make_float2(dv.x, mv.x);
        tm[cc][t4 + 1] = make_float2(dv.y, mv.y);
        tm[cc][t4 + 2] = make_float2(dv.z, mv.z);
        tm[cc][t4 + 3] = make_float2(dv.w, mv.w);
    }

    // ---- per-wave constants ----
    f16x8 Af[6];                                   // A: r0,r1,z0,z1,n0,n1
    float wrAn[8], wrBn[8], wzAn[8], wzBn[8];      // r/z: NEGATED x LOG2E
    float wnA[8], wnB[8];                          // n: x S2
    f32x4 Cn0 = {}, Cn1 = {};                      // n C-init (S2*bhh_n), const
    float hreg[8];
    f16x8 Afp[2];                                  // B: p0,p1 tiles (x S2)
    float wpA[8], wpB[8];                          // B: p C-init scalars
    float w2v[8], civ[8], civs = 0.0f, b2v = 0.0f; // B scalars

    const int ub = 8 * (c >> 2) + (c & 3);
    const int j0 = 8 * g;
    if (w == 0) {
#pragma unroll
        for (int T = 0; T < 6; ++T) {
            const int G = T >> 1, p = T & 1;
            const int up = ub + 4 * p;
            const float sc = (G < 2) ? -LOG2E : S2;
            const float* src =
                (G == 0) ? (w_hh + (size_t)up * 32 + j0) :
                (G == 1) ? (w_hh + (size_t)(32 + up) * 32 + j0) :
                           (w_hh + (size_t)(64 + up) * 32 + j0);
#pragma unroll
            for (int e = 0; e < 8; ++e) Af[T][e] = (_Float16)(src[e] * sc);
        }
#pragma unroll
        for (int e = 0; e < 8; ++e) {
            const int u = 8 * g + e;
            wrAn[e] = -w_ih[u] * LOG2E;
            wrBn[e] = -(b_ih[u] + b_hh[u]) * LOG2E;
            wzAn[e] = -w_ih[32 + u] * LOG2E;
            wzBn[e] = -(b_ih[32 + u] + b_hh[32 + u]) * LOG2E;
            wnA[e]  = w_ih[64 + u] * S2;
            wnB[e]  = b_ih[64 + u] * S2;
            hreg[e] = 0.0f;
        }
#pragma unroll
        for (int d = 0; d < 4; ++d) {
            Cn0[d] = b_hh[64 + 8 * g + d] * S2;
            Cn1[d] = b_hh[64 + 8 * g + 4 + d] * S2;
        }
    } else {
#pragma unroll
        for (int p = 0; p < 2; ++p) {
            const int up = ub + 4 * p;
            const float* src = w1 + (size_t)up * 33 + 1 + j0;
#pragma unroll
            for (int e = 0; e < 8; ++e) Afp[p][e] = (_Float16)(src[e] * S2);
        }
#pragma unroll
        for (int e = 0; e < 8; ++e) {
            const int u = 8 * g + e;
            wpA[e] = w1[(size_t)u * 33] * S2;
            wpB[e] = b1[u] * S2;
            w2v[e] = w2[u];
            civ[e] = w1[(size_t)u * 33] * w2v[e];
            civs  += civ[e];
        }
        b2v = b2[0];
    }

    __syncthreads();

    constexpr int NC = Ln / 16;          // 32 chunks

    // ---- loop-carried state for wave A: current step's C operands ----
    f32x4 Cr0, Cr1, Cz0, Cz1;
    float nbase[8];
    float mcur = 0.0f;
    if (w == 0) {
        const float2 t0v = tm[c][0];
        mcur = t0v.y;
#pragma unroll
        for (int d = 0; d < 4; ++d) {
            Cr0[d] = fmaf(t0v.x, wrAn[d],     wrBn[d]);
            Cr1[d] = fmaf(t0v.x, wrAn[4 + d], wrBn[4 + d]);
            Cz0[d] = fmaf(t0v.x, wzAn[d],     wzBn[d]);
            Cz1[d] = fmaf(t0v.x, wzAn[4 + d], wzBn[4 + d]);
        }
#pragma unroll
        for (int e = 0; e < 8; ++e) nbase[e] = fmaf(t0v.x, wnA[e], wnB[e]);
    }

    for (int chunk = 0; chunk <= NC; ++chunk) {
        if (w == 0 && chunk < NC) {
            const int tbase = chunk * 16;
            for (int s = 0; s < 16; ++s) {
                const int t = tbase + s;

                // ---- pack h -> f16 B-fragment (cvt_pkrtz) ----
                f16x8 bf;
#pragma unroll
                for (int e2 = 0; e2 < 4; ++e2) {
                    const auto pp = __builtin_amdgcn_cvt_pkrtz(hreg[2 * e2], hreg[2 * e2 + 1]);
                    bf[2 * e2]     = (_Float16)pp[0];
                    bf[2 * e2 + 1] = (_Float16)pp[1];
                }
                bfbuf[chunk & 1][s][c][g] = bf;     // for wave B (fire-and-forget)

                // ---- 6 MFMAs: r,z negated-scaled; n scaled ----
                f32x4 ar0 = __builtin_amdgcn_mfma_f32_16x16x32_f16(Af[0], bf, Cr0, 0, 0, 0);
                f32x4 ar1 = __builtin_amdgcn_mfma_f32_16x16x32_f16(Af[1], bf, Cr1, 0, 0, 0);
                f32x4 az0 = __builtin_amdgcn_mfma_f32_16x16x32_f16(Af[2], bf, Cz0, 0, 0, 0);
                f32x4 az1 = __builtin_amdgcn_mfma_f32_16x16x32_f16(Af[3], bf, Cz1, 0, 0, 0);
                f32x4 an0 = __builtin_amdgcn_mfma_f32_16x16x32_f16(Af[4], bf, Cn0, 0, 0, 0);
                f32x4 an1 = __builtin_amdgcn_mfma_f32_16x16x32_f16(Af[5], bf, Cn1, 0, 0, 0);

                // ---- MFMA-latency shadow: next step's C operands + nbase ----
                const float2 tmn = tm[c][(t + 1 < Ln) ? (t + 1) : t];
                f32x4 Nr0, Nr1, Nz0, Nz1;
                float nbn[8];
#pragma unroll
                for (int d = 0; d < 4; ++d) {
                    Nr0[d] = fmaf(tmn.x, wrAn[d],     wrBn[d]);
                    Nr1[d] = fmaf(tmn.x, wrAn[4 + d], wrBn[4 + d]);
                    Nz0[d] = fmaf(tmn.x, wzAn[d],     wzBn[d]);
                    Nz1[d] = fmaf(tmn.x, wzAn[4 + d], wzBn[4 + d]);
                }
#pragma unroll
                for (int e = 0; e < 8; ++e) nbn[e] = fmaf(tmn.x, wnA[e], wnB[e]);

                // ---- r,z: 16 exp2, order-pinned ----
                float er[8], ez[8];
#pragma unroll
                for (int d = 0; d < 4; ++d) er[d]     = aexp2(ar0[d]);
#pragma unroll
                for (int d = 0; d < 4; ++d) er[4 + d] = aexp2(ar1[d]);
#pragma unroll
                for (int d = 0; d < 4; ++d) ez[d]     = aexp2(az0[d]);
#pragma unroll
                for (int d = 0; d < 4; ++d) ez[4 + d] = aexp2(az1[d]);

                // ---- batched r/z reciprocal: 8 rcp for 16 sigmoids ----
                float ar_[8], az_[8], inv[8];
#pragma unroll
                for (int e = 0; e < 8; ++e) { ar_[e] = 1.0f + er[e]; az_[e] = 1.0f + ez[e]; }
#pragma unroll
                for (int e = 0; e < 8; ++e) inv[e] = arcp(ar_[e] * az_[e]);
                float rg[8], zg[8];
#pragma unroll
                for (int e = 0; e < 8; ++e) { rg[e] = inv[e] * az_[e]; zg[e] = inv[e] * ar_[e]; }

                // ---- n gate (no clamp; bounded) ----
                float npe[8];
#pragma unroll
                for (int e = 0; e < 8; ++e) {
                    const float accn = (e < 4) ? an0[e] : an1[e - 4];
                    npe[e] = fmaf(rg[e], accn, nbase[e]);
                }
                float nex[8];
#pragma unroll
                for (int e = 0; e < 8; ++e) nex[e] = aexp2(npe[e]);
                float nrc[8];
#pragma unroll
                for (int e = 0; e < 8; ++e) nrc[e] = arcp(1.0f + nex[e]);

                // ---- h update: h += m*(1-z)*(n - h) ----
#pragma unroll
                for (int e = 0; e < 8; ++e) {
                    const float nn = fmaf(-2.0f, nrc[e], 1.0f);
                    const float q  = fmaf(-zg[e], mcur, mcur);   // m*(1-z)
                    hreg[e] = fmaf(q, nn - hreg[e], hreg[e]);
                }

                // rotate loop-carried state
                Cr0 = Nr0; Cr1 = Nr1; Cz0 = Nz0; Cz1 = Nz1;
#pragma unroll
                for (int e = 0; e < 8; ++e) nbase[e] = nbn[e];
                mcur = tmn.y;
            }
        } else if (w == 1 && chunk > 0) {
            const int tbase = (chunk - 1) * 16;
            const int rb    = (chunk - 1) & 1;
#pragma unroll 2
            for (int s = 0; s < 16; ++s) {
                const f16x8 bfv = bfbuf[rb][s][c][g];
                const float tau = tm[c][tbase + s].x;
                f32x4 Cp0, Cp1;
#pragma unroll
                for (int d = 0; d < 4; ++d) {
                    Cp0[d] = fmaf(tau, wpA[d],     wpB[d]);
                    Cp1[d] = fmaf(tau, wpA[4 + d], wpB[4 + d]);
                }
                const f32x4 a0 = __builtin_amdgcn_mfma_f32_16x16x32_f16(Afp[0], bfv, Cp0, 0, 0, 0);
                const f32x4 a1 = __builtin_amdgcn_mfma_f32_16x16x32_f16(Afp[1], bfv, Cp1, 0, 0, 0);
                float aex[8];
#pragma unroll
                for (int e = 0; e < 8; ++e) aex[e] = aexp2((e < 4) ? a0[e] : a1[e - 4]);
                float arc[8];
#pragma unroll
                for (int e = 0; e < 8; ++e) arc[e] = arcp(1.0f + aex[e]);
                float v1p = 0.0f, v2p = civs;
#pragma unroll
                for (int e = 0; e < 8; ++e) {
                    const float a = fmaf(-2.0f, arc[e], 1.0f);
                    v1p = fmaf(a, w2v[e], v1p);
                    v2p = fmaf(a * a, -civ[e], v2p);
                }
                v1p += __shfl_xor(v1p, 16, 64);
                v1p += __shfl_xor(v1p, 32, 64);
                v2p += __shfl_xor(v2p, 16, 64);
                v2p += __shfl_xor(v2p, 32, 64);
                if (l < 16) {
                    PK2 pk;
                    pk.f[0] = (_Float16)(v1p + b2v);
                    pk.f[1] = (_Float16)v2p;
                    ibuf[l * 520 + tbase + s] = pk.u;
                }
            }
        }
        __syncthreads();
    }

    // ---- phase 2: LL transcendentals over 16 x 512 items, 128 threads ----
    float T = 0.0f, M = 0.0f;
#pragma unroll 4
    for (int it = 0; it < 64; ++it) {
        const int idx = it * 128 + tid;         // cc*512 + tt
        const int cc  = idx >> 9;
        const int tt  = idx & 511;
        PK2 pk; pk.u = ibuf[cc * 520 + tt];
        const float raw = (float)pk.f[0];
        const float v2  = (float)pk.f[1];
        const float mm  = tm[cc][tt].y;
        const float phi  = softplusf_(raw);
        const float dphi = sigmoidf_(raw) * v2;
        const float lam  = softplusf_(dphi) + EPSf;
        T = fmaf(__logf(lam) - phi, mm, T);
        M += mm;
    }
#pragma unroll
    for (int d = 1; d < 64; d <<= 1) {
        T += __shfl_xor(T, d, 64);
        M += __shfl_xor(M, d, 64);
    }
    __shared__ float sT[2], sM[2];
    if (l == 0) { sT[w] = T; sM[w] = M; }
    __syncthreads();
    if (tid == 0) {
        partials[blockIdx.x]             = sT[0] + sT[1];
        partials[gridDim.x + blockIdx.x] = sM[0] + sM[1];
    }
}

__global__ __launch_bounds__(256)
void tpp_final(const float* __restrict__ partials, int nparts,
               float* __restrict__ out)
{
    const int tid = threadIdx.x;
    double T = 0.0, M = 0.0;
    for (int k = tid; k < nparts; k += 256) {
        T += (double)partials[k];
        M += (double)partials[nparts + k];
    }
#pragma unroll
    for (int d = 1; d < 64; d <<= 1) {
        T += __shfl_xor(T, d, 64);
        M += __shfl_xor(M, d, 64);
    }
    __shared__ double sT[4], sM[4];
    const int w = tid >> 6;
    if ((tid & 63) == 0) { sT[w] = T; sM[w] = M; }
    __syncthreads();
    if (tid == 0) {
        const double t2 = sT[0] + sT[1] + sT[2] + sT[3];
        const double m2 = sM[0] + sM[1] + sM[2] + sM[3];
        out[0] = (float)(t2 / (m2 + (double)EPSf));
    }
}

extern "C" void kernel_launch(void* const* d_in, const int* in_sizes, int n_in,
                              void* d_out, int out_size, void* d_ws, size_t ws_size,
                              hipStream_t stream) {
    const float* deltas = (const float*)d_in[0];
    const float* mask   = (const float*)d_in[1];
    const float* w_ih   = (const float*)d_in[2];
    const float* w_hh   = (const float*)d_in[3];
    const float* b_ih   = (const float*)d_in[4];
    const float* b_hh   = (const float*)d_in[5];
    const float* w1     = (const float*)d_in[6];
    const float* b1     = (const float*)d_in[7];
    const float* w2     = (const float*)d_in[8];
    const float* b2     = (const float*)d_in[9];
    float* out = (float*)d_out;
    float* partials = (float*)d_ws;      // 2 * 256 * 4 B

    const int nblocks = Bn / 16;         // 256
    tpp_main<<<nblocks, 128, 0, stream>>>(deltas, mask, w_ih, w_hh, b_ih, b_hh,
                                          w1, b1, w2, b2, partials);
    tpp_final<<<1, 256, 0, stream>>>(partials, nblocks, out);
}